// Round 1
// baseline (373.009 us; speedup 1.0000x reference)
//
#include <hip/hip_runtime.h>

namespace {
constexpr int Bb  = 512;
constexpr int Nn  = 196;
constexpr int Cc  = 384;
constexpr int CT_ = 16;    // channels per block
constexpr int TPB = 128;   // 16 channels x 8 w-bins
constexpr int AP  = 17;    // padded stride for A in LDS (bank-conflict break)
}

// cos/sin(2*pi*k/14), k=0..13 (exact to fp32)
__device__ constexpr float HC[14] = {
   1.0f,                 0.9009688679024191f,  0.6234898018587336f,  0.22252093395631445f,
  -0.22252093395631445f, -0.6234898018587336f, -0.9009688679024191f, -1.0f,
  -0.9009688679024191f, -0.6234898018587336f, -0.22252093395631445f, 0.22252093395631445f,
   0.6234898018587336f,  0.9009688679024191f };
__device__ constexpr float HS[14] = {
   0.0f,                 0.43388373911755823f, 0.7818314824680298f,  0.9749279121818236f,
   0.9749279121818236f,  0.7818314824680298f,  0.43388373911755823f, 0.0f,
  -0.43388373911755823f, -0.7818314824680298f, -0.9749279121818236f, -0.9749279121818236f,
  -0.7818314824680298f, -0.43388373911755823f };

__global__ __launch_bounds__(TPB) void gf_kernel(
    const float* __restrict__ x, const float* __restrict__ wt,
    float* __restrict__ out) {
  __shared__ float S[Nn * CT_];          // x tile: [n][cl]
  __shared__ float ArL[14 * 8 * AP];     // A real: [(p*8+w)*AP + cl]
  __shared__ float AiL[14 * 8 * AP];     // A imag
  __shared__ float Ct[14];
  __shared__ float St[14];

  const int tid = threadIdx.x;
  const int b   = blockIdx.x;
  const int c0  = blockIdx.y * CT_;

  if (tid == 0) {
#pragma unroll
    for (int k = 0; k < 14; ++k) { Ct[k] = HC[k]; St[k] = HS[k]; }
  }

  // ---- stage 0: load x tile (coalesced 64B segments) ----
  const float* xb = x + (size_t)b * (Nn * Cc) + c0;
  for (int i = tid; i < Nn * CT_; i += TPB) {
    int n = i >> 4, cl = i & 15;
    S[i] = xb[n * Cc + cl];
  }
  __syncthreads();

  const int cl = tid & 15;   // channel within tile
  const int w  = tid >> 4;   // 0..7: the half-spectrum column this thread owns

  // w-dependent twiddles hoisted to registers (broadcast LDS reads)
  float cwv[14], swv[14];
  {
    int idx = 0;
#pragma unroll
    for (int v = 0; v < 14; ++v) {
      cwv[v] = Ct[idx]; swv[v] = St[idx];
      idx += w; if (idx >= 14) idx -= 14;
    }
  }

  // ---- stage 1: V[u] = sum_v S[u][v] * e^{-2pi i w v/14} ----
  float Vr[14], Vi[14];
#pragma unroll
  for (int u = 0; u < 14; ++u) {
    float vr = 0.f, vi = 0.f;
#pragma unroll
    for (int v = 0; v < 14; ++v) {
      float s = S[(u * 14 + v) * CT_ + cl];
      vr = fmaf(s,  cwv[v], vr);
      vi = fmaf(s, -swv[v], vi);
    }
    Vr[u] = vr; Vi[u] = vi;
  }

  // ---- stage 2: X[h] = sum_u V[u] * e^{-2pi i h u/14}  (twiddles fold to literals) ----
  float Xr[14], Xi[14];
#pragma unroll
  for (int h = 0; h < 14; ++h) {
    float xr = 0.f, xi = 0.f;
#pragma unroll
    for (int u = 0; u < 14; ++u) {
      const float c = HC[(h * u) % 14];
      const float s = HS[(h * u) % 14];
      xr += Vr[u] * c + Vi[u] * s;
      xi += Vi[u] * c - Vr[u] * s;
    }
    Xr[h] = xr; Xi[h] = xi;
  }

  // ---- stage 3: Y = X * W_c (complex pointwise), in place. wt[h][w][c][{re,im}] ----
  const float2* wp = reinterpret_cast<const float2*>(wt) + ((size_t)w * Cc + c0 + cl);
#pragma unroll
  for (int h = 0; h < 14; ++h) {
    float2 wc = wp[(size_t)h * (8 * Cc)];
    float yr = Xr[h] * wc.x - Xi[h] * wc.y;
    float yi = Xr[h] * wc.y + Xi[h] * wc.x;
    Xr[h] = yr; Xi[h] = yi;
  }

  // ---- stage 4: A[p] = (m_w/196) * sum_h Y[h] * e^{+2pi i h p/14} ----
  const float scale = ((w == 0 || w == 7) ? 1.f : 2.f) / 196.f;
#pragma unroll
  for (int p = 0; p < 14; ++p) {
    float ar = 0.f, ai = 0.f;
#pragma unroll
    for (int h = 0; h < 14; ++h) {
      const float c = HC[(p * h) % 14];
      const float s = HS[(p * h) % 14];
      ar += Xr[h] * c - Xi[h] * s;
      ai += Xi[h] * c + Xr[h] * s;
    }
    ArL[(p * 8 + w) * AP + cl] = ar * scale;
    AiL[(p * 8 + w) * AP + cl] = ai * scale;
  }
  __syncthreads();

  // ---- epilogue: out[p,q] = sum_w ArL*cos(2pi w q/14) - AiL*sin(2pi w q/14) ----
  float* ob = out + (size_t)b * (Nn * Cc) + c0;
  for (int i = tid; i < Nn * CT_; i += TPB) {
    int pq = i >> 4, c2 = i & 15;
    int p = pq / 14;
    int q = pq - p * 14;
    const float* arp = &ArL[(p * 8) * AP + c2];
    const float* aip = &AiL[(p * 8) * AP + c2];
    float acc = arp[0];                      // w=0: cos=1, sin=0 (Im ignored per c2r)
    float a7  = arp[7 * AP];                 // w=7: cos=(-1)^q, sin=0
    acc += (q & 1) ? -a7 : a7;
    int idx = q;                             // (w2*q)%14 running index
#pragma unroll
    for (int w2 = 1; w2 < 7; ++w2) {
      acc = fmaf(arp[w2 * AP],  Ct[idx], acc);
      acc = fmaf(-aip[w2 * AP], St[idx], acc);
      idx += q; if (idx >= 14) idx -= 14;
    }
    ob[pq * Cc + c2] = acc;
  }
}

extern "C" void kernel_launch(void* const* d_in, const int* in_sizes, int n_in,
                              void* d_out, int out_size, void* d_ws, size_t ws_size,
                              hipStream_t stream) {
  const float* x  = (const float*)d_in[0];
  const float* wt = (const float*)d_in[1];
  float* out      = (float*)d_out;
  dim3 grid(Bb, Cc / CT_);
  gf_kernel<<<grid, TPB, 0, stream>>>(x, wt, out);
}

// Round 2
// 321.409 us; speedup vs baseline: 1.1605x; 1.1605x over previous
//
#include <hip/hip_runtime.h>

namespace {
constexpr int Bb = 512, Nn = 196, Cc = 384, CT = 16, TPB = 128;
constexpr int SST = 212;        // S2 row stride (floats): rows 16B-aligned, banks 2-way (free)
constexpr int AST = 20;         // A2 channel stride (floats): 16B-aligned, banks 2-way (free)
constexpr int APS = CT * AST;   // A2 p-stride = 320 floats

constexpr float C7t[7] = {1.f, 0.6234898018587335f, -0.2225209339563144f,
                          -0.9009688679024191f, -0.9009688679024191f,
                          -0.2225209339563144f, 0.6234898018587335f};
constexpr float S7t[7] = {0.f, 0.7818314824680298f, 0.9749279121818236f,
                          0.4338837391175581f, -0.4338837391175581f,
                          -0.9749279121818236f, -0.7818314824680298f};
constexpr float C14t[14] = {1.f, 0.9009688679024191f, 0.6234898018587336f, 0.2225209339563144f,
                            -0.2225209339563144f, -0.6234898018587336f, -0.9009688679024191f, -1.f,
                            -0.9009688679024191f, -0.6234898018587336f, -0.2225209339563144f,
                            0.2225209339563144f, 0.6234898018587336f, 0.9009688679024191f};
constexpr float S14t[14] = {0.f, 0.4338837391175581f, 0.7818314824680298f, 0.9749279121818236f,
                            0.9749279121818236f, 0.7818314824680298f, 0.4338837391175581f, 0.f,
                            -0.4338837391175581f, -0.7818314824680298f, -0.9749279121818236f,
                            -0.9749279121818236f, -0.7818314824680298f, -0.4338837391175581f};
}

// Length-7 DFT via conjugate-pair symmetry. SG=+1: forward (e^{-i}); SG=-1: inverse.
template<int SG>
__device__ __forceinline__ void dft7(const float* vr, const float* vi, float* Er, float* Ei) {
  const float P1r = vr[1] + vr[6], M1r = vr[1] - vr[6];
  const float P1i = vi[1] + vi[6], M1i = vi[1] - vi[6];
  const float P2r = vr[2] + vr[5], M2r = vr[2] - vr[5];
  const float P2i = vi[2] + vi[5], M2i = vi[2] - vi[5];
  const float P3r = vr[3] + vr[4], M3r = vr[3] - vr[4];
  const float P3i = vi[3] + vi[4], M3i = vi[3] - vi[4];
  Er[0] = vr[0] + P1r + P2r + P3r;
  Ei[0] = vi[0] + P1i + P2i + P3i;
#pragma unroll
  for (int k = 1; k < 7; ++k) {
    const float c1 = C7t[k], c2 = C7t[(2 * k) % 7], c3 = C7t[(3 * k) % 7];
    const float s1 = SG * S7t[k], s2 = SG * S7t[(2 * k) % 7], s3 = SG * S7t[(3 * k) % 7];
    float er = fmaf(P1r, c1, vr[0]);
    er = fmaf(P2r, c2, er);
    er = fmaf(P3r, c3, er);
    er = fmaf(M1i, s1, er);
    er = fmaf(M2i, s2, er);
    er = fmaf(M3i, s3, er);
    float ei = fmaf(P1i, c1, vi[0]);
    ei = fmaf(P2i, c2, ei);
    ei = fmaf(P3i, c3, ei);
    ei = fmaf(M1r, -s1, ei);
    ei = fmaf(M2r, -s2, ei);
    ei = fmaf(M3r, -s3, ei);
    Er[k] = er; Ei[k] = ei;
  }
}

__global__ __launch_bounds__(TPB) void gf_kernel(const float* __restrict__ x,
                                                 const float* __restrict__ wt,
                                                 float* __restrict__ out) {
  __shared__ float S2[CT * SST];     // transposed x tile: [cl][n]
  __shared__ float A2[14 * APS];     // [p][cl][0..7]=Re w, [8..15]=Im w (pre-scaled)
  __shared__ float Ct[14], St[14];

  const int tid = threadIdx.x;
  const int b   = blockIdx.x;
  const int c0  = blockIdx.y * CT;

  if (tid < 14) { Ct[tid] = C14t[tid]; St[tid] = S14t[tid]; }

  // ---- stage 0: global -> LDS (transposed) ----
  const float* xb = x + (size_t)b * (Nn * Cc) + c0;
  for (int i = tid; i < Nn * CT; i += TPB) {
    const int n = i >> 4, c = i & 15;
    S2[c * SST + n] = xb[n * Cc + c];
  }
  __syncthreads();

  const int cl = tid & 15;
  const int w  = tid >> 4;

  // per-thread v-twiddles: cos/sin(2*pi*w*v/14)
  float cwv[14], swv[14];
  {
    int idx = 0;
#pragma unroll
    for (int v = 0; v < 14; ++v) {
      cwv[v] = Ct[idx]; swv[v] = St[idx];
      idx += w; if (idx >= 14) idx -= 14;
    }
  }

  // ---- stage 1: V[u] = sum_v S[u][v] e^{-2pi i w v/14}  (b128 LDS reads) ----
  float Vr[14], Vi[14];
#pragma unroll
  for (int u = 0; u < 14; ++u) { Vr[u] = 0.f; Vi[u] = 0.f; }
  const float* Srow = &S2[cl * SST];
#pragma unroll
  for (int j = 0; j < 49; ++j) {
    const float4 qd = *reinterpret_cast<const float4*>(&Srow[4 * j]);
    const float sv[4] = {qd.x, qd.y, qd.z, qd.w};
#pragma unroll
    for (int t = 0; t < 4; ++t) {
      const int e = 4 * j + t;
      const int u = e / 14, v = e % 14;
      Vr[u] = fmaf(sv[t],  cwv[v], Vr[u]);
      Vi[u] = fmaf(sv[t], -swv[v], Vi[u]);
    }
  }

  // preload weights (used after ~180 ops of DFT-7 work: latency hidden)
  const float2* wp = reinterpret_cast<const float2*>(wt) + ((size_t)w * Cc + c0 + cl);
  float2 wreg[14];
#pragma unroll
  for (int h = 0; h < 14; ++h) wreg[h] = wp[(size_t)h * (8 * Cc)];

  // ---- stage 2: X = DFT14(V), radix-2 (even/odd u) ----
  float evr[7], evi[7], odr[7], odi[7];
#pragma unroll
  for (int t = 0; t < 7; ++t) {
    evr[t] = Vr[2 * t];     evi[t] = Vi[2 * t];
    odr[t] = Vr[2 * t + 1]; odi[t] = Vi[2 * t + 1];
  }
  float Er[7], Ei[7], Qr[7], Qi[7];
  dft7<1>(evr, evi, Er, Ei);
  dft7<1>(odr, odi, Qr, Qi);
  float Xr[14], Xi[14];
  Xr[0] = Er[0] + Qr[0]; Xi[0] = Ei[0] + Qi[0];
  Xr[7] = Er[0] - Qr[0]; Xi[7] = Ei[0] - Qi[0];
#pragma unroll
  for (int h = 1; h < 7; ++h) {
    const float c = C14t[h], s = S14t[h];
    const float Tr = fmaf(Qr[h], c,  Qi[h] * s);   // omega14^h * O
    const float Ti = fmaf(Qi[h], c, -Qr[h] * s);
    Xr[h] = Er[h] + Tr;     Xi[h] = Ei[h] + Ti;
    Xr[h + 7] = Er[h] - Tr; Xi[h + 7] = Ei[h] - Ti;
  }

  // ---- stage 3: Y = X * W, with m_w/196 scale folded in ----
  const float scale = ((w == 0 || w == 7) ? 1.f : 2.f) / 196.f;
  float Yr[14], Yi[14];
#pragma unroll
  for (int h = 0; h < 14; ++h) {
    const float wr = wreg[h].x, wi = wreg[h].y;
    Yr[h] = (Xr[h] * wr - Xi[h] * wi) * scale;
    Yi[h] = (Xr[h] * wi + Xi[h] * wr) * scale;
  }

  // ---- stage 4: A[p] = sum_h Y[h] e^{+2pi i p h/14}, radix-2; store to LDS ----
#pragma unroll
  for (int t = 0; t < 7; ++t) {
    evr[t] = Yr[2 * t];     evi[t] = Yi[2 * t];
    odr[t] = Yr[2 * t + 1]; odi[t] = Yi[2 * t + 1];
  }
  dft7<-1>(evr, evi, Er, Ei);
  dft7<-1>(odr, odi, Qr, Qi);
  float* Ap = &A2[cl * AST + w];
  Ap[0 * APS]     = Er[0] + Qr[0];  Ap[0 * APS + 8] = Ei[0] + Qi[0];
  Ap[7 * APS]     = Er[0] - Qr[0];  Ap[7 * APS + 8] = Ei[0] - Qi[0];
#pragma unroll
  for (int p = 1; p < 7; ++p) {
    const float c = C14t[p], s = S14t[p];
    const float Tr = fmaf(Qr[p], c, -Qi[p] * s);   // conj(omega14^p) * O
    const float Ti = fmaf(Qi[p], c,  Qr[p] * s);
    Ap[p * APS]           = Er[p] + Tr;  Ap[p * APS + 8]       = Ei[p] + Ti;
    Ap[(p + 7) * APS]     = Er[p] - Tr;  Ap[(p + 7) * APS + 8] = Ei[p] - Ti;
  }
  __syncthreads();

  // ---- epilogue: one thread per (p, c): 4x b128 reads -> all 14 q outputs ----
  float* ob = out + (size_t)b * (Nn * Cc) + c0;
  for (int e = tid; e < 14 * CT; e += TPB) {
    const int c2 = e & 15, p = e >> 4;
    const float* ap = &A2[p * APS + c2 * AST];
    float a[16];
    *reinterpret_cast<float4*>(&a[0])  = *reinterpret_cast<const float4*>(&ap[0]);
    *reinterpret_cast<float4*>(&a[4])  = *reinterpret_cast<const float4*>(&ap[4]);
    *reinterpret_cast<float4*>(&a[8])  = *reinterpret_cast<const float4*>(&ap[8]);
    *reinterpret_cast<float4*>(&a[12]) = *reinterpret_cast<const float4*>(&ap[12]);
    float* op = ob + (p * 14) * Cc + c2;
#pragma unroll
    for (int q = 0; q < 14; ++q) {
      float acc = (q & 1) ? (a[0] - a[7]) : (a[0] + a[7]);
#pragma unroll
      for (int w2 = 1; w2 < 7; ++w2) {
        const float c = C14t[(w2 * q) % 14];
        const float s = S14t[(w2 * q) % 14];
        acc = fmaf(a[w2], c, acc);
        acc = fmaf(a[8 + w2], -s, acc);
      }
      op[q * Cc] = acc;
    }
  }
}

extern "C" void kernel_launch(void* const* d_in, const int* in_sizes, int n_in,
                              void* d_out, int out_size, void* d_ws, size_t ws_size,
                              hipStream_t stream) {
  const float* x  = (const float*)d_in[0];
  const float* wt = (const float*)d_in[1];
  float* out      = (float*)d_out;
  dim3 grid(Bb, Cc / CT);
  gf_kernel<<<grid, TPB, 0, stream>>>(x, wt, out);
}

// Round 3
// 313.252 us; speedup vs baseline: 1.1908x; 1.0260x over previous
//
#include <hip/hip_runtime.h>

namespace {
constexpr int Bb = 512, Nn = 196, Cc = 384, CT = 16, TPB = 128;
constexpr int SST = 212;        // S view: row stride (floats), 16B-aligned, 2-way banks (free)
constexpr int AST = 20;         // A view: channel stride (floats), 16B-aligned, 2-way banks (free)
constexpr int APS = CT * AST;   // A view: p stride = 320 floats
constexpr int USZ = 14 * APS;   // union size = 4480 floats (>= 16*212 = 3392)

constexpr float C7t[7] = {1.f, 0.6234898018587335f, -0.2225209339563144f,
                          -0.9009688679024191f, -0.9009688679024191f,
                          -0.2225209339563144f, 0.6234898018587335f};
constexpr float S7t[7] = {0.f, 0.7818314824680298f, 0.9749279121818236f,
                          0.4338837391175581f, -0.4338837391175581f,
                          -0.9749279121818236f, -0.7818314824680298f};
constexpr float C14t[14] = {1.f, 0.9009688679024191f, 0.6234898018587336f, 0.2225209339563144f,
                            -0.2225209339563144f, -0.6234898018587336f, -0.9009688679024191f, -1.f,
                            -0.9009688679024191f, -0.6234898018587336f, -0.2225209339563144f,
                            0.2225209339563144f, 0.6234898018587336f, 0.9009688679024191f};
constexpr float S14t[14] = {0.f, 0.4338837391175581f, 0.7818314824680298f, 0.9749279121818236f,
                            0.9749279121818236f, 0.7818314824680298f, 0.4338837391175581f, 0.f,
                            -0.4338837391175581f, -0.7818314824680298f, -0.9749279121818236f,
                            -0.9749279121818236f, -0.7818314824680298f, -0.4338837391175581f};
}

// Length-7 complex DFT via conjugate-pair symmetry. SG=+1 forward, SG=-1 inverse.
template<int SG>
__device__ __forceinline__ void dft7(const float* vr, const float* vi, float* Er, float* Ei) {
  const float P1r = vr[1] + vr[6], M1r = vr[1] - vr[6];
  const float P1i = vi[1] + vi[6], M1i = vi[1] - vi[6];
  const float P2r = vr[2] + vr[5], M2r = vr[2] - vr[5];
  const float P2i = vi[2] + vi[5], M2i = vi[2] - vi[5];
  const float P3r = vr[3] + vr[4], M3r = vr[3] - vr[4];
  const float P3i = vi[3] + vi[4], M3i = vi[3] - vi[4];
  Er[0] = vr[0] + P1r + P2r + P3r;
  Ei[0] = vi[0] + P1i + P2i + P3i;
#pragma unroll
  for (int k = 1; k < 7; ++k) {
    const float c1 = C7t[k], c2 = C7t[(2 * k) % 7], c3 = C7t[(3 * k) % 7];
    const float s1 = SG * S7t[k], s2 = SG * S7t[(2 * k) % 7], s3 = SG * S7t[(3 * k) % 7];
    float er = fmaf(P1r, c1, vr[0]);
    er = fmaf(P2r, c2, er);
    er = fmaf(P3r, c3, er);
    er = fmaf(M1i, s1, er);
    er = fmaf(M2i, s2, er);
    er = fmaf(M3i, s3, er);
    float ei = fmaf(P1i, c1, vi[0]);
    ei = fmaf(P2i, c2, ei);
    ei = fmaf(P3i, c3, ei);
    ei = fmaf(M1r, -s1, ei);
    ei = fmaf(M2r, -s2, ei);
    ei = fmaf(M3r, -s3, ei);
    Er[k] = er; Ei[k] = ei;
  }
}

__global__ __launch_bounds__(TPB) void gf_kernel(const float* __restrict__ x,
                                                 const float* __restrict__ wt,
                                                 float* __restrict__ out) {
  // Union buffer: phase 1 = transposed x tile S[cl][n] (stride SST);
  //               phase 2 = spectrum A[p][cl][0..7]=Re_w, [8..15]=Im_w (stride AST).
  // S is fully consumed into registers before A is written (barrier between).
  __shared__ float U[USZ];
  __shared__ float Ct[14], St[14];

  const int tid = threadIdx.x;
  const int b   = blockIdx.x;
  const int c0  = blockIdx.y * CT;

  if (tid < 14) { Ct[tid] = C14t[tid]; St[tid] = S14t[tid]; }

  // ---- stage 0: global -> LDS (transposed) ----
  const float* xb = x + (size_t)b * (Nn * Cc) + c0;
  for (int i = tid; i < Nn * CT; i += TPB) {
    const int n = i >> 4, c = i & 15;
    U[c * SST + n] = xb[n * Cc + c];
  }
  __syncthreads();

  const int cl = tid & 15;
  const int w  = tid >> 4;

  // per-thread v-twiddles: cos/sin(2*pi*w*v/14) (broadcast LDS reads)
  float cwv[14], swv[14];
  {
    int idx = 0;
#pragma unroll
    for (int v = 0; v < 14; ++v) {
      cwv[v] = Ct[idx]; swv[v] = St[idx];
      idx += w; if (idx >= 14) idx -= 14;
    }
  }

  // ---- stage 1: V[u] = sum_v S[u][v] e^{-2pi i w v/14}  (b128 LDS reads) ----
  float Vr[14], Vi[14];
#pragma unroll
  for (int u = 0; u < 14; ++u) { Vr[u] = 0.f; Vi[u] = 0.f; }
  const float* Srow = &U[cl * SST];
#pragma unroll
  for (int j = 0; j < 49; ++j) {
    const float4 qd = *reinterpret_cast<const float4*>(&Srow[4 * j]);
    const float sv[4] = {qd.x, qd.y, qd.z, qd.w};
#pragma unroll
    for (int t = 0; t < 4; ++t) {
      const int e = 4 * j + t;
      const int u = e / 14, v = e % 14;
      Vr[u] = fmaf(sv[t],  cwv[v], Vr[u]);
      Vi[u] = fmaf(sv[t], -swv[v], Vi[u]);
    }
  }

  // issue weight loads BEFORE the barrier so they're in flight across it
  const float2* wp = reinterpret_cast<const float2*>(wt) + ((size_t)w * Cc + c0 + cl);
  float2 wreg[14];
#pragma unroll
  for (int h = 0; h < 14; ++h) wreg[h] = wp[(size_t)h * (8 * Cc)];

  __syncthreads();   // S fully read; U may now be overwritten as A

  // ---- stage 2: X = DFT14(V), radix-2 (even/odd u) ----
  float evr[7], evi[7], odr[7], odi[7];
#pragma unroll
  for (int t = 0; t < 7; ++t) {
    evr[t] = Vr[2 * t];     evi[t] = Vi[2 * t];
    odr[t] = Vr[2 * t + 1]; odi[t] = Vi[2 * t + 1];
  }
  float Er[7], Ei[7], Qr[7], Qi[7];
  dft7<1>(evr, evi, Er, Ei);
  dft7<1>(odr, odi, Qr, Qi);
  float Xr[14], Xi[14];
  Xr[0] = Er[0] + Qr[0]; Xi[0] = Ei[0] + Qi[0];
  Xr[7] = Er[0] - Qr[0]; Xi[7] = Ei[0] - Qi[0];
#pragma unroll
  for (int h = 1; h < 7; ++h) {
    const float c = C14t[h], s = S14t[h];
    const float Tr = fmaf(Qr[h], c,  Qi[h] * s);   // omega14^h * O
    const float Ti = fmaf(Qi[h], c, -Qr[h] * s);
    Xr[h] = Er[h] + Tr;     Xi[h] = Ei[h] + Ti;
    Xr[h + 7] = Er[h] - Tr; Xi[h + 7] = Ei[h] - Ti;
  }

  // ---- stage 3: Y = X * W, with m_w/196 scale folded in ----
  const float scale = ((w == 0 || w == 7) ? 1.f : 2.f) / 196.f;
  float Yr[14], Yi[14];
#pragma unroll
  for (int h = 0; h < 14; ++h) {
    const float wr = wreg[h].x, wi = wreg[h].y;
    Yr[h] = (Xr[h] * wr - Xi[h] * wi) * scale;
    Yi[h] = (Xr[h] * wi + Xi[h] * wr) * scale;
  }

  // ---- stage 4: A[p] = sum_h Y[h] e^{+2pi i p h/14}, radix-2; store to LDS ----
#pragma unroll
  for (int t = 0; t < 7; ++t) {
    evr[t] = Yr[2 * t];     evi[t] = Yi[2 * t];
    odr[t] = Yr[2 * t + 1]; odi[t] = Yi[2 * t + 1];
  }
  dft7<-1>(evr, evi, Er, Ei);
  dft7<-1>(odr, odi, Qr, Qi);
  float* Ap = &U[cl * AST + w];
  Ap[0 * APS]     = Er[0] + Qr[0];  Ap[0 * APS + 8] = Ei[0] + Qi[0];
  Ap[7 * APS]     = Er[0] - Qr[0];  Ap[7 * APS + 8] = Ei[0] - Qi[0];
#pragma unroll
  for (int p = 1; p < 7; ++p) {
    const float c = C14t[p], s = S14t[p];
    const float Tr = fmaf(Qr[p], c, -Qi[p] * s);   // conj(omega14^p) * O
    const float Ti = fmaf(Qi[p], c,  Qr[p] * s);
    Ap[p * APS]           = Er[p] + Tr;  Ap[p * APS + 8]       = Ei[p] + Ti;
    Ap[(p + 7) * APS]     = Er[p] - Tr;  Ap[(p + 7) * APS + 8] = Ei[p] - Ti;
  }
  __syncthreads();

  // ---- epilogue: thread per (p,c); q<->14-q symmetry shares cos/sin sums ----
  float* ob = out + (size_t)b * (Nn * Cc) + c0;
  for (int e = tid; e < 14 * CT; e += TPB) {
    const int c2 = e & 15, p = e >> 4;
    const float* ap = &U[p * APS + c2 * AST];
    float a[16];
    *reinterpret_cast<float4*>(&a[0])  = *reinterpret_cast<const float4*>(&ap[0]);
    *reinterpret_cast<float4*>(&a[4])  = *reinterpret_cast<const float4*>(&ap[4]);
    *reinterpret_cast<float4*>(&a[8])  = *reinterpret_cast<const float4*>(&ap[8]);
    *reinterpret_cast<float4*>(&a[12]) = *reinterpret_cast<const float4*>(&ap[12]);
    float* op = ob + (p * 14) * Cc + c2;
    // q = 0: sum of Re; q = 7: alternating sum of Re (sin terms vanish)
    op[0]       = ((a[0] + a[7]) + (a[1] + a[2])) + ((a[3] + a[4]) + (a[5] + a[6]));
    op[7 * Cc]  = ((a[0] - a[7]) - (a[1] - a[2])) - ((a[3] - a[4]) + (a[5] - a[6]));
#pragma unroll
    for (int q = 1; q < 7; ++q) {
      float cs = (q & 1) ? (a[0] - a[7]) : (a[0] + a[7]);
      float ss = 0.f;
#pragma unroll
      for (int w2 = 1; w2 < 7; ++w2) {
        const float c = C14t[(w2 * q) % 14];
        const float s = S14t[(w2 * q) % 14];
        cs = fmaf(a[w2], c, cs);
        ss = fmaf(a[8 + w2], s, ss);
      }
      op[q * Cc]        = cs - ss;
      op[(14 - q) * Cc] = cs + ss;
    }
  }
}

extern "C" void kernel_launch(void* const* d_in, const int* in_sizes, int n_in,
                              void* d_out, int out_size, void* d_ws, size_t ws_size,
                              hipStream_t stream) {
  const float* x  = (const float*)d_in[0];
  const float* wt = (const float*)d_in[1];
  float* out      = (float*)d_out;
  dim3 grid(Bb, Cc / CT);
  gf_kernel<<<grid, TPB, 0, stream>>>(x, wt, out);
}